// Round 8
// baseline (660.945 us; speedup 1.0000x reference)
//
#include <hip/hip_runtime.h>

#define B_ 512
#define T_ 512
#define V_ 96
#define H_ 128
#define K2F 2.8853900817779268f   // 2*log2(e): exp(2s) == exp2(K2F*s)

typedef _Float16 h2_t __attribute__((ext_vector_type(2)));

__device__ __forceinline__ h2_t as_h2(unsigned u) {
    union { unsigned u; h2_t h; } v; v.u = u; return v.h;
}
__device__ __forceinline__ unsigned as_u32(h2_t h) {
    union { h2_t h; unsigned u; } v; v.h = h; return v.u;
}
// v_cvt_pkrtz_f16_f32: pack 2 fp32 -> 2 fp16 (RTZ), return raw dword
__device__ __forceinline__ unsigned pkrtz_u32(float a, float b) {
    auto r = __builtin_amdgcn_cvt_pkrtz(a, b);
    union { decltype(r) h; unsigned u; } v; v.h = r; return v.u;
}
__device__ __forceinline__ float fdot2(h2_t a, h2_t b, float c) {
#if __has_builtin(__builtin_amdgcn_fdot2)
    return __builtin_amdgcn_fdot2(a, b, c, false);
#else
    return fmaf((float)a.x, (float)b.x, fmaf((float)a.y, (float)b.y, c));
#endif
}

// Pass 1a: recover the one-hot index per (b,t). x is exactly {0.0, 1.0}.
__global__ __launch_bounds__(256) void onehot_idx_kernel(
    const float4* __restrict__ x4, int n4, int* __restrict__ idx)
{
    int stride = gridDim.x * blockDim.x;
    for (int e4 = blockIdx.x * blockDim.x + threadIdx.x; e4 < n4; e4 += stride) {
        float4 v = x4[e4];
        int base = e4 * 4;
        if (v.x > 0.5f) idx[(base + 0) / V_] = (base + 0) % V_;
        if (v.y > 0.5f) idx[(base + 1) / V_] = (base + 1) % V_;
        if (v.z > 0.5f) idx[(base + 2) / V_] = (base + 2) % V_;
        if (v.w > 0.5f) idx[(base + 3) / V_] = (base + 3) % V_;
    }
}

// Pass 1b: xwT[v][h] = (W_ih[h][v] + b_ih[h] + b_hh[h]) * K2F  (fp32, global)
__global__ __launch_bounds__(256) void build_xwT_kernel(
    const float* __restrict__ W_ih, const float* __restrict__ b_ih,
    const float* __restrict__ b_hh, float* __restrict__ xwT)
{
    int e = blockIdx.x * blockDim.x + threadIdx.x;
    if (e < V_ * H_) {
        int v = e >> 7, h = e & 127;
        xwT[e] = (W_ih[h * V_ + v] + b_ih[h] + b_hh[h]) * K2F;
    }
}

// Pass 1c: pack W_hh to fp16 pairs, laid out for the rnn kernel's loads:
//   uint4 wA[j4] = whhp4[j4*128 + 2*lane + 0]   (unit 2*lane)
//   uint4 wB[j4] = whhp4[j4*128 + 2*lane + 1]   (unit 2*lane+1)
// dword c of whhp4[idx4] = pack(W_hh[unit][2j], W_hh[unit][2j+1]), j = j4*4+c.
__global__ __launch_bounds__(256) void build_whhp_kernel(
    const float* __restrict__ W_hh, unsigned* __restrict__ whhp)
{
    int D = blockIdx.x * blockDim.x + threadIdx.x;   // 0 .. 8191
    if (D < 64 * H_) {
        int idx4 = D >> 2, c = D & 3;
        int j4   = idx4 >> 7;
        int rem  = idx4 & 127;
        int lane = rem >> 1;
        int m    = rem & 1;
        int unit = 2 * lane + m;
        int j    = j4 * 4 + c;
        h2_t pk;
        pk.x = (_Float16)W_hh[unit * H_ + 2 * j];
        pk.y = (_Float16)W_hh[unit * H_ + 2 * j + 1];
        whhp[D] = as_u32(pk);
    }
}

// Pass 2: ONE WAVE per batch row; h state lives in 64 wave-uniform dwords
// (SGPRs) -- zero LDS / DS-pipe ops in the recurrence, no barriers.
// Lane l owns units {2l, 2l+1}: 128 packed-fp16 weight dwords in regs.
// Step: 128 v_dot2_f32_f16 (SGPR h operand) -> 2x tanh -> pkrtz ->
// 64x v_readlane rebuilds hs[]. xw gather: global, prefetched 2 steps ahead.
__global__ __launch_bounds__(64) void rnn_wave_kernel(
    const uint4* __restrict__ whhp4, const float* __restrict__ xwT,
    const int*  __restrict__ idx,
    const float* __restrict__ W_fc, const float* __restrict__ b_fc,
    float* __restrict__ out)
{
    const int b = blockIdx.x;
    const int l = threadIdx.x;       // 0..63

    __shared__ int idx_s[T_ + 2];

    for (int e = l; e < T_; e += 64) idx_s[e] = idx[b * T_ + e];
    if (l < 2) idx_s[T_ + l] = 0;    // pad for t+2 prefetch

    // weights: unit A = 2l, unit B = 2l+1; K-pairs j = j4*4+c
    uint4 wA[16], wB[16];
    #pragma unroll
    for (int j4 = 0; j4 < 16; ++j4) {
        wA[j4] = whhp4[j4 * 128 + 2 * l + 0];
        wB[j4] = whhp4[j4 * 128 + 2 * l + 1];
    }

    unsigned hs[64];                 // wave-uniform packed h (SGPR-resident)
    #pragma unroll
    for (int j = 0; j < 64; ++j) hs[j] = 0u;

    // 2-deep xw pipeline (single wave: own LDS writes ordered by lgkmcnt)
    float2 xw0 = *(const float2*)(xwT + idx_s[0] * H_ + 2 * l);
    float2 xw1 = *(const float2*)(xwT + idx_s[1] * H_ + 2 * l);

    for (int t = 0; t < T_; ++t) {
        // prefetch xw for t+2 (idx ds_read -> L2 load: ~2 steps of slack)
        const int idn = idx_s[t + 2];
        const float2 xw2 = *(const float2*)(xwT + idn * H_ + 2 * l);

        float aA0 = 0.f, aA1 = 0.f, aB0 = 0.f, aB1 = 0.f;
        #pragma unroll
        for (int j4 = 0; j4 < 16; ++j4) {
            const unsigned wa[4] = {wA[j4].x, wA[j4].y, wA[j4].z, wA[j4].w};
            const unsigned wb[4] = {wB[j4].x, wB[j4].y, wB[j4].z, wB[j4].w};
            #pragma unroll
            for (int c = 0; c < 4; ++c) {
                const h2_t hh = as_h2(hs[j4 * 4 + c]);
                if (c & 1) {
                    aA1 = fdot2(hh, as_h2(wa[c]), aA1);
                    aB1 = fdot2(hh, as_h2(wb[c]), aB1);
                } else {
                    aA0 = fdot2(hh, as_h2(wa[c]), aA0);
                    aB0 = fdot2(hh, as_h2(wb[c]), aB0);
                }
            }
        }
        const float sA = aA0 + aA1, sB = aB0 + aB1;
        // tanh(s) = 1 - 2/(exp2(K2F*s + xw) + 1); xw pre-scaled & bias-folded
        const float eA = __builtin_amdgcn_exp2f(fmaf(sA, K2F, xw0.x));
        const float eB = __builtin_amdgcn_exp2f(fmaf(sB, K2F, xw0.y));
        const float hA = 1.0f - 2.0f * __builtin_amdgcn_rcpf(eA + 1.0f);
        const float hB = 1.0f - 2.0f * __builtin_amdgcn_rcpf(eB + 1.0f);

        const int hpk = (int)pkrtz_u32(hA, hB);   // pack(h[2l], h[2l+1])
        #pragma unroll
        for (int j = 0; j < 64; ++j)
            hs[j] = (unsigned)__builtin_amdgcn_readlane(hpk, j);

        xw0 = xw1; xw1 = xw2;
    }

    // fc on final h (hs[] is wave-uniform: every lane has the full state).
    // lane l -> outputs v = l (l<64) and v = l+64 (l<32); V_=96.
    #pragma unroll
    for (int r = 0; r < 2; ++r) {
        const int v = l + r * 64;
        if (v < V_) {
            float acc = b_fc[v];
            const float4* wf = (const float4*)(W_fc + v * H_);
            #pragma unroll 8
            for (int j2 = 0; j2 < 32; ++j2) {     // 2 packed h pairs per float4
                const float4 wv = wf[j2];
                const h2_t h01 = as_h2(hs[2 * j2]);
                const h2_t h23 = as_h2(hs[2 * j2 + 1]);
                acc = fmaf((float)h01.x, wv.x, acc);
                acc = fmaf((float)h01.y, wv.y, acc);
                acc = fmaf((float)h23.x, wv.z, acc);
                acc = fmaf((float)h23.y, wv.w, acc);
            }
            out[b * V_ + v] = acc;
        }
    }
}

extern "C" void kernel_launch(void* const* d_in, const int* in_sizes, int n_in,
                              void* d_out, int out_size, void* d_ws, size_t ws_size,
                              hipStream_t stream)
{
    const float* x    = (const float*)d_in[0];
    const float* W_ih = (const float*)d_in[1];
    const float* b_ih = (const float*)d_in[2];
    const float* W_hh = (const float*)d_in[3];
    const float* b_hh = (const float*)d_in[4];
    const float* W_fc = (const float*)d_in[5];
    const float* b_fc = (const float*)d_in[6];
    float* out = (float*)d_out;

    int*      idx  = (int*)d_ws;                                    // 1 MiB
    float*    xwT  = (float*)((char*)d_ws + (size_t)B_ * T_ * 4);   // 48 KiB
    unsigned* whhp = (unsigned*)((char*)xwT + (size_t)V_ * H_ * 4); // 32 KiB

    const int n4 = (B_ * T_ * V_) / 4;
    hipLaunchKernelGGL(onehot_idx_kernel, dim3(2048), dim3(256), 0, stream,
                       (const float4*)x, n4, idx);
    hipLaunchKernelGGL(build_xwT_kernel, dim3((V_ * H_ + 255) / 256), dim3(256),
                       0, stream, W_ih, b_ih, b_hh, xwT);
    hipLaunchKernelGGL(build_whhp_kernel, dim3((64 * H_ + 255) / 256), dim3(256),
                       0, stream, W_hh, whhp);
    hipLaunchKernelGGL(rnn_wave_kernel, dim3(B_), dim3(64), 0, stream,
                       (const uint4*)whhp, xwT, idx, W_fc, b_fc, out);
}

// Round 9
// 474.081 us; speedup vs baseline: 1.3942x; 1.3942x over previous
//
#include <hip/hip_runtime.h>

#define B_ 512
#define T_ 512
#define V_ 96
#define H_ 128
#define K2F 2.8853900817779268f   // 2*log2(e): exp(2s) == exp2(K2F*s)

typedef _Float16 h2_t __attribute__((ext_vector_type(2)));

__device__ __forceinline__ h2_t as_h2(unsigned u) {
    union { unsigned u; h2_t h; } v; v.u = u; return v.h;
}
__device__ __forceinline__ unsigned as_u32(h2_t h) {
    union { h2_t h; unsigned u; } v; v.h = h; return v.u;
}
// v_cvt_pkrtz_f16_f32: pack 2 fp32 -> 2 fp16, return raw dword
__device__ __forceinline__ unsigned pkrtz_u32(float a, float b) {
    auto r = __builtin_amdgcn_cvt_pkrtz(a, b);
    union { decltype(r) h; unsigned u; } v; v.h = r; return v.u;
}
__device__ __forceinline__ float fdot2(h2_t a, h2_t b, float c) {
#if __has_builtin(__builtin_amdgcn_fdot2)
    return __builtin_amdgcn_fdot2(a, b, c, false);
#else
    return fmaf((float)a.x, (float)b.x, fmaf((float)a.y, (float)b.y, c));
#endif
}
template<int CTRL>
__device__ __forceinline__ float dpp_add(float x) {
    int y = __builtin_amdgcn_update_dpp(0, __float_as_int(x), CTRL, 0xF, 0xF, true);
    return x + __int_as_float(y);
}

// Pass 1a: recover the one-hot index per (b,t). x is exactly {0.0, 1.0}.
__global__ __launch_bounds__(256) void onehot_idx_kernel(
    const float4* __restrict__ x4, int n4, int* __restrict__ idx)
{
    int stride = gridDim.x * blockDim.x;
    for (int e4 = blockIdx.x * blockDim.x + threadIdx.x; e4 < n4; e4 += stride) {
        float4 v = x4[e4];
        int base = e4 * 4;
        if (v.x > 0.5f) idx[(base + 0) / V_] = (base + 0) % V_;
        if (v.y > 0.5f) idx[(base + 1) / V_] = (base + 1) % V_;
        if (v.z > 0.5f) idx[(base + 2) / V_] = (base + 2) % V_;
        if (v.w > 0.5f) idx[(base + 3) / V_] = (base + 3) % V_;
    }
}

// Pass 1b: xwT[v][h] = (W_ih[h][v] + b_ih[h] + b_hh[h]) * K2F  (fp32, global)
__global__ __launch_bounds__(256) void build_xwT_kernel(
    const float* __restrict__ W_ih, const float* __restrict__ b_ih,
    const float* __restrict__ b_hh, float* __restrict__ xwT)
{
    int e = blockIdx.x * blockDim.x + threadIdx.x;
    if (e < V_ * H_) {
        int v = e >> 7, h = e & 127;
        xwT[e] = (W_ih[h * V_ + v] + b_ih[h] + b_hh[h]) * K2F;
    }
}

// Pass 1c: pack W_hh into per-lane fp16 dwords (R7 layout, validated).
// rnn load: uint4 w4[r4] = whh2_u4[r4*64 + lane]; reg r = 4*r4+j;
// unit m = r>>5; pair p = r&31; value = pack(W_hh[4*(l>>1)+m][(l&1)*64+2p], +1)
__global__ __launch_bounds__(256) void build_whh2_kernel(
    const float* __restrict__ W_hh, unsigned* __restrict__ whh2)
{
    int D = blockIdx.x * blockDim.x + threadIdx.x;
    if (D < 64 * H_) {
        int r4  = D >> 8;
        int rem = D & 255;
        int l   = rem >> 2;
        int j   = rem & 3;
        int r   = (r4 << 2) + j;
        int m   = r >> 5;
        int p   = r & 31;
        int unit = ((l >> 1) << 2) + m;
        int k    = ((l & 1) << 6) + (p << 1);
        h2_t pk;
        pk.x = (_Float16)W_hh[unit * H_ + k];
        pk.y = (_Float16)W_hh[unit * H_ + k + 1];
        whh2[D] = as_u32(pk);
    }
}

// Pass 2: ONE WAVE per TWO batch rows -- two independent recurrence chains
// interleaved in one wave so each row's LDS latency hides under the other
// row's dot-issue. No barriers (single wave, lgkmcnt ordering). Per row,
// R7's mapping: lane = (c = l&1 K-half, units u0..u0+3); weights shared
// across rows (128 packed-fp16 VGPRs). K-reduce: 1 DPP xor1 per unit.
__global__ __launch_bounds__(64) void rnn_wave2_kernel(
    const uint4* __restrict__ whh2, const float* __restrict__ xwT,
    const int*  __restrict__ idx,
    const float* __restrict__ W_fc, const float* __restrict__ b_fc,
    float* __restrict__ out)
{
    const int b  = blockIdx.x;       // rows 2b, 2b+1
    const int l  = threadIdx.x;      // 0..63
    const int c  = l & 1;            // K-half
    const int u0 = (l >> 1) << 2;    // first of this lane's 4 units

    __shared__ int      idx_s[2][T_ + 2];
    __shared__ _Float16 hbuf[2][2][H_];   // [row][buf][unit]

    for (int e = l; e < T_; e += 64) {
        idx_s[0][e] = idx[(2 * b + 0) * T_ + e];
        idx_s[1][e] = idx[(2 * b + 1) * T_ + e];
    }
    if (l < 2) { idx_s[0][T_ + l] = 0; idx_s[1][T_ + l] = 0; }
    ((unsigned*)&hbuf[0][0][0])[l] = 0u;   // zero row0 buf0 (64 dwords)
    ((unsigned*)&hbuf[1][0][0])[l] = 0u;   // zero row1 buf0

    uint4 w4[32];                    // shared weights: 128 dwords
    #pragma unroll
    for (int r4 = 0; r4 < 32; ++r4) w4[r4] = whh2[r4 * 64 + l];

    int cur = 0;
    float4 xwa = *(const float4*)(xwT + idx_s[0][0] * H_ + u0);
    float4 xwb = *(const float4*)(xwT + idx_s[1][0] * H_ + u0);

    for (int t = 0; t < T_; ++t) {
        // prefetch next step's gathers (global, L2; ~600cy slack, no drain)
        const float4 xwan = *(const float4*)(xwT + idx_s[0][t + 1] * H_ + u0);
        const float4 xwbn = *(const float4*)(xwT + idx_s[1][t + 1] * H_ + u0);

        // both rows' K-half of h: 2 x 8 broadcast b128 reads
        const uint4* hp0 = (const uint4*)((const char*)&hbuf[0][cur][0] + (c << 7));
        const uint4* hp1 = (const uint4*)((const char*)&hbuf[1][cur][0] + (c << 7));
        uint4 h0[8], h1[8];
        #pragma unroll
        for (int i = 0; i < 8; ++i) { h0[i] = hp0[i]; h1[i] = hp1[i]; }

        float a00 = 0.f, a01 = 0.f, a02 = 0.f, a03 = 0.f;   // row0, units 0..3
        float a10 = 0.f, a11 = 0.f, a12 = 0.f, a13 = 0.f;   // row1
        #pragma unroll
        for (int p4 = 0; p4 < 8; ++p4) {
            const unsigned hx0[4] = {h0[p4].x, h0[p4].y, h0[p4].z, h0[p4].w};
            const unsigned hx1[4] = {h1[p4].x, h1[p4].y, h1[p4].z, h1[p4].w};
            const unsigned wx0[4] = {w4[ 0+p4].x, w4[ 0+p4].y, w4[ 0+p4].z, w4[ 0+p4].w};
            const unsigned wx1[4] = {w4[ 8+p4].x, w4[ 8+p4].y, w4[ 8+p4].z, w4[ 8+p4].w};
            const unsigned wx2[4] = {w4[16+p4].x, w4[16+p4].y, w4[16+p4].z, w4[16+p4].w};
            const unsigned wx3[4] = {w4[24+p4].x, w4[24+p4].y, w4[24+p4].z, w4[24+p4].w};
            #pragma unroll
            for (int j = 0; j < 4; ++j) {
                const h2_t g0 = as_h2(hx0[j]);
                const h2_t g1 = as_h2(hx1[j]);
                a00 = fdot2(g0, as_h2(wx0[j]), a00);
                a10 = fdot2(g1, as_h2(wx0[j]), a10);
                a01 = fdot2(g0, as_h2(wx1[j]), a01);
                a11 = fdot2(g1, as_h2(wx1[j]), a11);
                a02 = fdot2(g0, as_h2(wx2[j]), a02);
                a12 = fdot2(g1, as_h2(wx2[j]), a12);
                a03 = fdot2(g0, as_h2(wx3[j]), a03);
                a13 = fdot2(g1, as_h2(wx3[j]), a13);
            }
        }
        // combine K-halves (lane c^1): one DPP xor1 per accumulator
        a00 = dpp_add<0xB1>(a00); a01 = dpp_add<0xB1>(a01);
        a02 = dpp_add<0xB1>(a02); a03 = dpp_add<0xB1>(a03);
        a10 = dpp_add<0xB1>(a10); a11 = dpp_add<0xB1>(a11);
        a12 = dpp_add<0xB1>(a12); a13 = dpp_add<0xB1>(a13);

        // tanh(s) = 1 - 2/(exp2(K2F*s + xw) + 1); xw pre-scaled & bias-folded
        const float e00 = __builtin_amdgcn_exp2f(fmaf(a00, K2F, xwa.x));
        const float e01 = __builtin_amdgcn_exp2f(fmaf(a01, K2F, xwa.y));
        const float e02 = __builtin_amdgcn_exp2f(fmaf(a02, K2F, xwa.z));
        const float e03 = __builtin_amdgcn_exp2f(fmaf(a03, K2F, xwa.w));
        const float e10 = __builtin_amdgcn_exp2f(fmaf(a10, K2F, xwb.x));
        const float e11 = __builtin_amdgcn_exp2f(fmaf(a11, K2F, xwb.y));
        const float e12 = __builtin_amdgcn_exp2f(fmaf(a12, K2F, xwb.z));
        const float e13 = __builtin_amdgcn_exp2f(fmaf(a13, K2F, xwb.w));
        const float v00 = 1.0f - 2.0f * __builtin_amdgcn_rcpf(e00 + 1.0f);
        const float v01 = 1.0f - 2.0f * __builtin_amdgcn_rcpf(e01 + 1.0f);
        const float v02 = 1.0f - 2.0f * __builtin_amdgcn_rcpf(e02 + 1.0f);
        const float v03 = 1.0f - 2.0f * __builtin_amdgcn_rcpf(e03 + 1.0f);
        const float v10 = 1.0f - 2.0f * __builtin_amdgcn_rcpf(e10 + 1.0f);
        const float v11 = 1.0f - 2.0f * __builtin_amdgcn_rcpf(e11 + 1.0f);
        const float v12 = 1.0f - 2.0f * __builtin_amdgcn_rcpf(e12 + 1.0f);
        const float v13 = 1.0f - 2.0f * __builtin_amdgcn_rcpf(e13 + 1.0f);

        if (c == 0) {   // 32 lanes write 8B per row (2-way bank alias: free)
            *(uint2*)((char*)&hbuf[0][cur ^ 1][0] + (u0 << 1)) =
                make_uint2(pkrtz_u32(v00, v01), pkrtz_u32(v02, v03));
            *(uint2*)((char*)&hbuf[1][cur ^ 1][0] + (u0 << 1)) =
                make_uint2(pkrtz_u32(v10, v11), pkrtz_u32(v12, v13));
        }
        cur ^= 1;
        xwa = xwan; xwb = xwbn;
    }

    // fc on both final hidden states (one-time; scalar LDS reads fine)
    #pragma unroll
    for (int r = 0; r < 2; ++r) {
        const _Float16* hf = &hbuf[r][cur][0];
        for (int v = l; v < V_; v += 64) {
            float acc = b_fc[v];
            const float4* wf = (const float4*)(W_fc + v * H_);
            #pragma unroll 8
            for (int k4 = 0; k4 < 32; ++k4) {
                float4 wv = wf[k4];
                acc = fmaf((float)hf[4 * k4 + 0], wv.x, acc);
                acc = fmaf((float)hf[4 * k4 + 1], wv.y, acc);
                acc = fmaf((float)hf[4 * k4 + 2], wv.z, acc);
                acc = fmaf((float)hf[4 * k4 + 3], wv.w, acc);
            }
            out[(2 * b + r) * V_ + v] = acc;
        }
    }
}

extern "C" void kernel_launch(void* const* d_in, const int* in_sizes, int n_in,
                              void* d_out, int out_size, void* d_ws, size_t ws_size,
                              hipStream_t stream)
{
    const float* x    = (const float*)d_in[0];
    const float* W_ih = (const float*)d_in[1];
    const float* b_ih = (const float*)d_in[2];
    const float* W_hh = (const float*)d_in[3];
    const float* b_hh = (const float*)d_in[4];
    const float* W_fc = (const float*)d_in[5];
    const float* b_fc = (const float*)d_in[6];
    float* out = (float*)d_out;

    int*      idx  = (int*)d_ws;                                    // 1 MiB
    float*    xwT  = (float*)((char*)d_ws + (size_t)B_ * T_ * 4);   // 48 KiB
    unsigned* whh2 = (unsigned*)((char*)xwT + (size_t)V_ * H_ * 4); // 32 KiB

    const int n4 = (B_ * T_ * V_) / 4;
    hipLaunchKernelGGL(onehot_idx_kernel, dim3(2048), dim3(256), 0, stream,
                       (const float4*)x, n4, idx);
    hipLaunchKernelGGL(build_xwT_kernel, dim3((V_ * H_ + 255) / 256), dim3(256),
                       0, stream, W_ih, b_ih, b_hh, xwT);
    hipLaunchKernelGGL(build_whh2_kernel, dim3((64 * H_ + 255) / 256), dim3(256),
                       0, stream, W_hh, whh2);
    hipLaunchKernelGGL(rnn_wave2_kernel, dim3(B_ / 2), dim3(64), 0, stream,
                       (const uint4*)whh2, xwT, idx, W_fc, b_fc, out);
}

// Round 10
// 272.328 us; speedup vs baseline: 2.4270x; 1.7408x over previous
//
#include <hip/hip_runtime.h>

#define B_ 512
#define T_ 512
#define V_ 96
#define H_ 128
#define K2F 2.8853900817779268f   // 2*log2(e): exp(2s) == exp2(K2F*s)

typedef _Float16 h2_t __attribute__((ext_vector_type(2)));

__device__ __forceinline__ h2_t as_h2(unsigned u) {
    union { unsigned u; h2_t h; } v; v.u = u; return v.h;
}
__device__ __forceinline__ unsigned as_u32(h2_t h) {
    union { h2_t h; unsigned u; } v; v.h = h; return v.u;
}
// v_cvt_pkrtz_f16_f32: pack 2 fp32 -> 2 fp16, return raw dword
__device__ __forceinline__ unsigned pkrtz_u32(float a, float b) {
    auto r = __builtin_amdgcn_cvt_pkrtz(a, b);
    union { decltype(r) h; unsigned u; } v; v.h = r; return v.u;
}
__device__ __forceinline__ float fdot2(h2_t a, h2_t b, float c) {
#if __has_builtin(__builtin_amdgcn_fdot2)
    return __builtin_amdgcn_fdot2(a, b, c, false);
#else
    return fmaf((float)a.x, (float)b.x, fmaf((float)a.y, (float)b.y, c));
#endif
}
template<int CTRL>
__device__ __forceinline__ float dpp_add(float x) {
    int y = __builtin_amdgcn_update_dpp(0, __float_as_int(x), CTRL, 0xF, 0xF, true);
    return x + __int_as_float(y);
}

// Pass 1a: recover the one-hot index per (b,t). x is exactly {0.0, 1.0}.
__global__ __launch_bounds__(256) void onehot_idx_kernel(
    const float4* __restrict__ x4, int n4, int* __restrict__ idx)
{
    int stride = gridDim.x * blockDim.x;
    for (int e4 = blockIdx.x * blockDim.x + threadIdx.x; e4 < n4; e4 += stride) {
        float4 v = x4[e4];
        int base = e4 * 4;
        if (v.x > 0.5f) idx[(base + 0) / V_] = (base + 0) % V_;
        if (v.y > 0.5f) idx[(base + 1) / V_] = (base + 1) % V_;
        if (v.z > 0.5f) idx[(base + 2) / V_] = (base + 2) % V_;
        if (v.w > 0.5f) idx[(base + 3) / V_] = (base + 3) % V_;
    }
}

// Pass 1b: xwT[v][h] = (W_ih[h][v] + b_ih[h] + b_hh[h]) * K2F  (fp32, global)
__global__ __launch_bounds__(256) void build_xwT_kernel(
    const float* __restrict__ W_ih, const float* __restrict__ b_ih,
    const float* __restrict__ b_hh, float* __restrict__ xwT)
{
    int e = blockIdx.x * blockDim.x + threadIdx.x;
    if (e < V_ * H_) {
        int v = e >> 7, h = e & 127;
        xwT[e] = (W_ih[h * V_ + v] + b_ih[h] + b_hh[h]) * K2F;
    }
}

// Pass 1c: pack W_hh into per-lane fp16 dwords (R7 layout, validated).
// rnn load: uint4 w4[r4] = whh2_u4[r4*64 + lane]; reg r = 4*r4+j;
// unit m = r>>5; pair p = r&31; value = pack(W_hh[4*(l>>1)+m][(l&1)*64+2p], +1)
__global__ __launch_bounds__(256) void build_whh2_kernel(
    const float* __restrict__ W_hh, unsigned* __restrict__ whh2)
{
    int D = blockIdx.x * blockDim.x + threadIdx.x;
    if (D < 64 * H_) {
        int r4  = D >> 8;
        int rem = D & 255;
        int l   = rem >> 2;
        int j   = rem & 3;
        int r   = (r4 << 2) + j;
        int m   = r >> 5;
        int p   = r & 31;
        int unit = ((l >> 1) << 2) + m;
        int k    = ((l & 1) << 6) + (p << 1);
        h2_t pk;
        pk.x = (_Float16)W_hh[unit * H_ + k];
        pk.y = (_Float16)W_hh[unit * H_ + k + 1];
        whh2[D] = as_u32(pk);
    }
}

// Pass 2: ONE WAVE per batch row -- no barriers in the step loop.
// __launch_bounds__(64, 1): allow the full 512-VGPR budget so the 128
// packed-fp16 weight dwords STAY IN REGISTERS (R7/R9 showed VGPR_Count=84:
// the compiler was spilling them to scratch and reloading every step --
// that was the hidden 70% of the step time).
// lane = (c = l&1 K-half, units u0..u0+3). h: fp16 in LDS (broadcast reads).
// K-reduce: single DPP xor1. xw gather: global L2, prefetched 1 step ahead.
__global__ __launch_bounds__(64, 1) void rnn_wave_kernel(
    const uint4* __restrict__ whh2, const float* __restrict__ xwT,
    const int*  __restrict__ idx,
    const float* __restrict__ W_fc, const float* __restrict__ b_fc,
    float* __restrict__ out)
{
    const int b  = blockIdx.x;
    const int l  = threadIdx.x;      // 0..63
    const int c  = l & 1;            // K-half
    const int u0 = (l >> 1) << 2;    // first of this lane's 4 units

    __shared__ int      idx_s[T_];
    __shared__ _Float16 hbuf[2][H_];

    for (int e = l; e < T_; e += 64) idx_s[e] = idx[b * T_ + e];
    hbuf[0][l]      = (_Float16)0.f;
    hbuf[0][l + 64] = (_Float16)0.f;

    uint4 w4[32];                    // 128 dwords: MUST be VGPR-resident
    #pragma unroll
    for (int r4 = 0; r4 < 32; ++r4) w4[r4] = whh2[r4 * 64 + l];

    int cur = 0;
    float4 xw = *(const float4*)(xwT + idx_s[0] * H_ + u0);

    for (int t = 0; t < T_; ++t) {
        // prefetch next step's gather: global load, ~1 full step of slack
        const int idn = idx_s[(t + 1) & (T_ - 1)];
        const float4 xwn = *(const float4*)(xwT + idn * H_ + u0);

        // this lane's K-half of h: 8 broadcast b128 reads
        const uint4* hp = (const uint4*)((const char*)&hbuf[cur][0] + (c << 7));
        uint4 h4[8];
        #pragma unroll
        for (int i = 0; i < 8; ++i) h4[i] = hp[i];

        float a0 = 0.f, a1 = 0.f, a2 = 0.f, a3 = 0.f;
        #pragma unroll
        for (int p4 = 0; p4 < 8; ++p4) {
            const unsigned hx[4] = {h4[p4].x, h4[p4].y, h4[p4].z, h4[p4].w};
            const unsigned wx0[4] = {w4[ 0+p4].x, w4[ 0+p4].y, w4[ 0+p4].z, w4[ 0+p4].w};
            const unsigned wx1[4] = {w4[ 8+p4].x, w4[ 8+p4].y, w4[ 8+p4].z, w4[ 8+p4].w};
            const unsigned wx2[4] = {w4[16+p4].x, w4[16+p4].y, w4[16+p4].z, w4[16+p4].w};
            const unsigned wx3[4] = {w4[24+p4].x, w4[24+p4].y, w4[24+p4].z, w4[24+p4].w};
            #pragma unroll
            for (int j = 0; j < 4; ++j) {
                const h2_t hh = as_h2(hx[j]);
                a0 = fdot2(hh, as_h2(wx0[j]), a0);
                a1 = fdot2(hh, as_h2(wx1[j]), a1);
                a2 = fdot2(hh, as_h2(wx2[j]), a2);
                a3 = fdot2(hh, as_h2(wx3[j]), a3);
            }
        }
        // add partner K-half (lane c^1): single DPP xor1 stage
        a0 = dpp_add<0xB1>(a0); a1 = dpp_add<0xB1>(a1);
        a2 = dpp_add<0xB1>(a2); a3 = dpp_add<0xB1>(a3);

        // tanh(s) = 1 - 2/(exp2(K2F*s + xw) + 1)   (fp32)
        float e0 = __builtin_amdgcn_exp2f(fmaf(a0, K2F, xw.x));
        float e1 = __builtin_amdgcn_exp2f(fmaf(a1, K2F, xw.y));
        float e2 = __builtin_amdgcn_exp2f(fmaf(a2, K2F, xw.z));
        float e3 = __builtin_amdgcn_exp2f(fmaf(a3, K2F, xw.w));
        float h0 = 1.0f - 2.0f * __builtin_amdgcn_rcpf(e0 + 1.0f);
        float h1 = 1.0f - 2.0f * __builtin_amdgcn_rcpf(e1 + 1.0f);
        float h2v = 1.0f - 2.0f * __builtin_amdgcn_rcpf(e2 + 1.0f);
        float h3 = 1.0f - 2.0f * __builtin_amdgcn_rcpf(e3 + 1.0f);

        if (c == 0) {                         // 32 lanes write 8B each (2-way: free)
            *(uint2*)((char*)&hbuf[cur ^ 1][0] + (u0 << 1)) =
                make_uint2(pkrtz_u32(h0, h1), pkrtz_u32(h2v, h3));
        }
        cur ^= 1;
        xw = xwn;
    }

    // fc on final hidden state (one-time; scalar LDS reads are fine here)
    for (int v = l; v < V_; v += 64) {
        float acc = b_fc[v];
        const float4* wf = (const float4*)(W_fc + v * H_);
        #pragma unroll 8
        for (int k4 = 0; k4 < 32; ++k4) {
            float4 wv = wf[k4];
            acc = fmaf((float)hbuf[cur][4 * k4 + 0], wv.x, acc);
            acc = fmaf((float)hbuf[cur][4 * k4 + 1], wv.y, acc);
            acc = fmaf((float)hbuf[cur][4 * k4 + 2], wv.z, acc);
            acc = fmaf((float)hbuf[cur][4 * k4 + 3], wv.w, acc);
        }
        out[b * V_ + v] = acc;
    }
}

extern "C" void kernel_launch(void* const* d_in, const int* in_sizes, int n_in,
                              void* d_out, int out_size, void* d_ws, size_t ws_size,
                              hipStream_t stream)
{
    const float* x    = (const float*)d_in[0];
    const float* W_ih = (const float*)d_in[1];
    const float* b_ih = (const float*)d_in[2];
    const float* W_hh = (const float*)d_in[3];
    const float* b_hh = (const float*)d_in[4];
    const float* W_fc = (const float*)d_in[5];
    const float* b_fc = (const float*)d_in[6];
    float* out = (float*)d_out;

    int*      idx  = (int*)d_ws;                                    // 1 MiB
    float*    xwT  = (float*)((char*)d_ws + (size_t)B_ * T_ * 4);   // 48 KiB
    unsigned* whh2 = (unsigned*)((char*)xwT + (size_t)V_ * H_ * 4); // 32 KiB

    const int n4 = (B_ * T_ * V_) / 4;
    hipLaunchKernelGGL(onehot_idx_kernel, dim3(2048), dim3(256), 0, stream,
                       (const float4*)x, n4, idx);
    hipLaunchKernelGGL(build_xwT_kernel, dim3((V_ * H_ + 255) / 256), dim3(256),
                       0, stream, W_ih, b_ih, b_hh, xwT);
    hipLaunchKernelGGL(build_whh2_kernel, dim3((64 * H_ + 255) / 256), dim3(256),
                       0, stream, W_hh, whh2);
    hipLaunchKernelGGL(rnn_wave_kernel, dim3(B_), dim3(64), 0, stream,
                       (const uint4*)whh2, xwT, idx, W_fc, b_fc, out);
}